// Round 8
// baseline (23.647 us; speedup 1.0000x reference)
//
#include <hip/hip_runtime.h>
#include <math.h>

// Problem constants (fixed by setup_inputs).
namespace {
constexpr int Cc = 81, Hc = 112, Wc = 200, Mc = 20;
constexpr int BN   = 12;            // B*N
constexpr int HW   = Hc * Wc;       // 22400 (div by 4; NOT by 256 -> per-quad bn)
constexpr int NPIX = BN * HW;       // 268800
constexpr int PPB  = 256;           // pixels per block
constexpr int TPB  = 256;           // 4 waves; each wave covers all 256 pixels
constexpr int NBLK = NPIX / PPB;    // 1050 — exact
constexpr float kAlpha = 0.25f;
constexpr float kFgW   = 13.0f;
constexpr float kBgW   = 1.0f;
constexpr float kInvDS = 0.125f;    // 1/8 exact pow-2: x*kInvDS == x/8
}

// Pass 1. Block = 4 waves over the same 256 pixels; wave y sums exp() over
// classes [20y,20y+20) (wave 3 also takes class 80). Lane holds a float4
// quad -> each class-plane load is a 1 KB contiguous wave request.
// R8 change (isolated): ALL 20 loads issued up front into v[20]
// (compile-time indices -> VGPRs, ~145 VGPR, no spill), consumed in issue
// order so the compiler emits stepwise vmcnt waits -> ONE latency exposure
// per wave and 20 KB in flight throughout (R7 drained vmcnt between two
// 10-deep batches -> half the outstanding bytes, two stalls).
__global__ __launch_bounds__(TPB) void ddn_pass1(
    const float* __restrict__ logits,   // [BN, C, H, W]
    const int*   __restrict__ target,   // [BN, H, W]
    const float* __restrict__ boxes,    // [BN, M, 4] (x, y, w, h)
    float*       __restrict__ partial)  // [NBLK]
{
    __shared__ float sh[4][PPB];        // per-wave partial sums, 4 KB
    __shared__ float wsum[4];

    const int t    = threadIdx.x;
    const int lane = t & 63;
    const int wv   = t >> 6;            // wave-uniform
    const int pixb = blockIdx.x * PPB;

    // Early: this thread's epilogue pixel -> target gather (hides under loop).
    const int  epix = pixb + t;
    const int  ebn  = epix / HW;
    const int  ehw  = epix - ebn * HW;
    const int  etgt = target[epix];     // coalesced 256 B per wave
    const float xt  = logits[(size_t)ebn * Cc * HW + (size_t)etgt * HW + ehw];

    // Main: lane's quad = pixels pixb+4*lane .. +3 (HW%4==0 -> quad never
    // straddles a row or bn, even though 256-pixel blocks can straddle bn).
    const int qpix = pixb + lane * 4;
    const int qbn  = qpix / HW;
    const int qhw  = qpix - qbn * HW;
    const float4* lp4 = reinterpret_cast<const float4*>(
        logits + (size_t)qbn * Cc * HW + qhw);
    const int c0 = wv * 20;

    float4 v[20];
    #pragma unroll
    for (int j = 0; j < 20; ++j)
        v[j] = lp4[(size_t)(c0 + j) * (HW / 4)];

    float a0 = 0.f, a1 = 0.f, a2 = 0.f, a3 = 0.f;
    #pragma unroll
    for (int j = 0; j < 20; ++j) {      // consume oldest-first -> stepwise vmcnt
        a0 += __expf(v[j].x);
        a1 += __expf(v[j].y);
        a2 += __expf(v[j].z);
        a3 += __expf(v[j].w);
    }
    if (wv == 3) {                      // leftover class 80 (wave-uniform)
        const float4 u = lp4[(size_t)80 * (HW / 4)];
        a0 += __expf(u.x); a1 += __expf(u.y);
        a2 += __expf(u.z); a3 += __expf(u.w);
    }
    reinterpret_cast<float4*>(sh[wv])[lane] = make_float4(a0, a1, a2, a3);
    __syncthreads();

    // Epilogue: one thread per pixel. sh[y][t] reads are conflict-free
    // (2 lanes/bank = free on CDNA4).
    const float s    = sh[0][t] + sh[1][t] + sh[2][t] + sh[3][t];
    const float lpt  = xt - __logf(s);  // log_pt (no max-subtract: ~N(0,1))
    const float om   = 1.f - __expf(lpt);
    const float loss = -kAlpha * om * om * lpt;

    // fg mask: any of 20 boxes (feature-res rect) covers pixel.
    const int h = ehw / Wc;
    const int w = ehw - h * Wc;
    const float hf = (float)h, wf = (float)w;
    const float* bx = boxes + (size_t)ebn * Mc * 4;
    bool fg = false;
    #pragma unroll
    for (int m = 0; m < Mc; ++m) {
        const float bxx = bx[m * 4 + 0];
        const float bxy = bx[m * 4 + 1];
        const float u1 = floorf(bxx * kInvDS);
        const float v1 = floorf(bxy * kInvDS);
        const float u2 = ceilf((bxx + bx[m * 4 + 2]) * kInvDS);
        const float v2 = ceilf((bxy + bx[m * 4 + 3]) * kInvDS);
        fg |= (hf >= v1) & (hf < v2) & (wf >= u1) & (wf < u2);
    }
    float local = loss * (fg ? kFgW : kBgW);

    // Block reduce -> one plain store per block.
    #pragma unroll
    for (int off = 32; off > 0; off >>= 1)
        local += __shfl_down(local, off, 64);
    if ((t & 63) == 0) wsum[t >> 6] = local;
    __syncthreads();
    if (t == 0)
        partial[blockIdx.x] = wsum[0] + wsum[1] + wsum[2] + wsum[3];
}

// Pass 2: reduce the NBLK per-block partials, write the scalar output.
__global__ __launch_bounds__(1024) void ddn_pass2(
    const float* __restrict__ partial, float* __restrict__ out)
{
    const int t = threadIdx.x;
    float s = 0.f;
    for (int i = t; i < NBLK; i += 1024)
        s += partial[i];
    #pragma unroll
    for (int off = 32; off > 0; off >>= 1)
        s += __shfl_down(s, off, 64);
    __shared__ float smem[16];
    if ((t & 63) == 0) smem[t >> 6] = s;
    __syncthreads();
    if (t < 64) {
        float z = (t < 16) ? smem[t] : 0.f;
        #pragma unroll
        for (int off = 8; off > 0; off >>= 1)
            z += __shfl_down(z, off, 64);
        if (t == 0) out[0] = z * (1.0f / (float)NPIX);
    }
}

extern "C" void kernel_launch(void* const* d_in, const int* in_sizes, int n_in,
                              void* d_out, int out_size, void* d_ws, size_t ws_size,
                              hipStream_t stream) {
    const float* logits = (const float*)d_in[0];  // depth_logits f32
    const int*   target = (const int*)d_in[1];    // depth_target i32
    const float* boxes  = (const float*)d_in[2];  // gt_bboxes_2d f32
    float* out     = (float*)d_out;
    float* partial = (float*)d_ws;                // NBLK floats, fully rewritten

    ddn_pass1<<<NBLK, TPB, 0, stream>>>(logits, target, boxes, partial);
    ddn_pass2<<<1, 1024, 0, stream>>>(partial, out);
}